// Round 1
// baseline (326.290 us; speedup 1.0000x reference)
//
#include <hip/hip_runtime.h>
#include <math.h>

// Workspace float offsets
#define OFF_AT  0         // At  [256 h][64 r]   : A[r][h] transposed, w(h) folded
#define OFF_BMT 16384     // BmT [256 w][32 y]   : w(w) folded
#define OFF_CMT 24576     // CmT [64 r][256 h]   : mode-weight folded
#define OFF_DMT 40960     // DmT [32 y][256 w]   : y-weight folded
#define OFF_Y   49152     // Y [8][64][64 r][32 y]
#define OFF_Z   1097728   // Z [8][64][64 r][32 y]

__device__ __forceinline__ float cosT(int p) {
    // cos(pi * p / 255), exact integer argument reduction to [0, pi]
    int r = p % 510;
    if (r > 255) r = 510 - r;
    return cosf((float)r * (3.14159265358979323846f / 255.0f));
}

__global__ __launch_bounds__(256) void init_basis(float* __restrict__ ws) {
    int idx = blockIdx.x * 256 + threadIdx.x;
    if (idx < 16384) {                       // At[h][r]
        int h = idx >> 6, r = idx & 63;
        int k1 = (r < 32) ? r : r + 192;
        float we = (h == 0 || h == 255) ? 1.f : 2.f;
        ws[OFF_AT + idx] = we * cosT(k1 * h);
    } else if (idx < 24576) {                // BmT[w][y]
        int j = idx - 16384; int w = j >> 5, y = j & 31;
        float we = (w == 0 || w == 255) ? 1.f : 2.f;
        ws[OFF_BMT + j] = we * cosT(y * w);
    } else if (idx < 40960) {                // CmT[r][h]
        int j = idx - 24576; int r = j >> 8, h = j & 255;
        int k1 = (r < 32) ? r : r + 192;
        float wsl = (r == 0 || r == 63) ? 1.f : 2.f;
        ws[OFF_CMT + j] = wsl * cosT(k1 * h);
    } else if (idx < 49152) {                // DmT[y][w]
        int j = idx - 40960; int y = j >> 8, w = j & 255;
        float wy = (y == 0) ? 1.f : 2.f;
        ws[OFF_DMT + j] = wy * cosT(y * w);
    }
}

// ---------------- forward projection: Y[b,i,r,y] ----------------
__global__ __launch_bounds__(256) void fwd_kernel(const float* __restrict__ x,
                                                  const float* __restrict__ ws,
                                                  float* __restrict__ Y) {
    __shared__ float buf[9216];   // stage1: x chunk [256][33]; stage2: T1 [256][36]
    __shared__ float bmt[1024];   // BmT chunk [32 w][32 y]
    const int t = threadIdx.x;
    const int bi = blockIdx.x;
    const float* xp = x + (size_t)bi * 65536;
    const int l = t & 63;
    const int y8 = (t >> 6) * 8;

    float acc[4][8];
#pragma unroll
    for (int j = 0; j < 4; ++j)
#pragma unroll
        for (int yy = 0; yy < 8; ++yy) acc[j][yy] = 0.f;

    const int colv = (t & 7) * 4;
    const int rbase = t >> 3;

    for (int c = 0; c < 8; ++c) {
        // stage x chunk cols [c*32, c*32+32) into LDS (coalesced 128B/row-segment)
#pragma unroll
        for (int r = 0; r < 8; ++r) {
            int row = r * 32 + rbase;
            float4 v = *(const float4*)(xp + row * 256 + c * 32 + colv);
            float* dst = &buf[row * 33 + colv];
            dst[0] = v.x; dst[1] = v.y; dst[2] = v.z; dst[3] = v.w;
        }
        {
            int wloc = t >> 3;
            int y4 = (t & 7) * 4;
            *(float4*)&bmt[wloc * 32 + y4] =
                *(const float4*)(ws + OFF_BMT + (c * 32 + wloc) * 32 + y4);
        }
        __syncthreads();
#pragma unroll 8
        for (int w = 0; w < 32; ++w) {
            float xv0 = buf[l * 33 + w];            // bank = (l+w)%32: conflict-free
            float xv1 = buf[(l + 64) * 33 + w];
            float xv2 = buf[(l + 128) * 33 + w];
            float xv3 = buf[(l + 192) * 33 + w];
            float4 b0 = *(float4*)&bmt[w * 32 + y8];      // wave-uniform: broadcast
            float4 b1 = *(float4*)&bmt[w * 32 + y8 + 4];
            float bv[8] = {b0.x, b0.y, b0.z, b0.w, b1.x, b1.y, b1.z, b1.w};
#pragma unroll
            for (int yy = 0; yy < 8; ++yy) {
                acc[0][yy] += xv0 * bv[yy];
                acc[1][yy] += xv1 * bv[yy];
                acc[2][yy] += xv2 * bv[yy];
                acc[3][yy] += xv3 * bv[yy];
            }
        }
        __syncthreads();
    }
    // write T1 into buf viewed as [256][36] (16B-aligned rows for stage-2 b128 broadcast)
#pragma unroll
    for (int j = 0; j < 4; ++j)
#pragma unroll
        for (int yy = 0; yy < 8; ++yy)
            buf[(l + 64 * j) * 36 + y8 + yy] = acc[j][yy];
    __syncthreads();

    // stage 2: Y[r][y] = sum_h At[h][r] * T1[h][y]
    float acc2[8];
#pragma unroll
    for (int yy = 0; yy < 8; ++yy) acc2[yy] = 0.f;
    const float* At = ws + OFF_AT;
#pragma unroll 4
    for (int h = 0; h < 256; ++h) {
        float av = At[h * 64 + l];                 // lane-consecutive: coalesced, L2-hot
        float4 t0 = *(float4*)&buf[h * 36 + y8];   // wave-uniform broadcast
        float4 t1 = *(float4*)&buf[h * 36 + y8 + 4];
        acc2[0] += av * t0.x; acc2[1] += av * t0.y;
        acc2[2] += av * t0.z; acc2[3] += av * t0.w;
        acc2[4] += av * t1.x; acc2[5] += av * t1.y;
        acc2[6] += av * t1.z; acc2[7] += av * t1.w;
    }
    float* Yp = Y + (size_t)bi * 2048 + l * 32 + y8;
    *(float4*)Yp       = make_float4(acc2[0], acc2[1], acc2[2], acc2[3]);
    *(float4*)(Yp + 4) = make_float4(acc2[4], acc2[5], acc2[6], acc2[7]);
}

// ---------------- per-mode channel mixing: Z[b,o,r,y] ----------------
__global__ __launch_bounds__(256) void mix_kernel(const float* __restrict__ w1,
                                                  const float* __restrict__ w2,
                                                  const float* __restrict__ Yv,
                                                  float* __restrict__ Z) {
    const int xp = blockIdx.x & 63;          // mode row r (0..63)
    const int o0 = (blockIdx.x >> 6) * 16;   // 4 o-quarters
    const int t = threadIdx.x;
    const int yh = t & 15;                   // y = 2*yh (y fastest: coalesced W stream)
    const int oo = t >> 4;
    const int o = o0 + oo;
    const int y = yh * 2;

    const float* Wbase = (xp < 32) ? (w1 + xp * 32) : (w2 + (xp - 32) * 32);
    Wbase += o * 1024 + y;
    const float* Yb = Yv + xp * 32 + y;

    float acc[8][2];
#pragma unroll
    for (int b = 0; b < 8; ++b) { acc[b][0] = 0.f; acc[b][1] = 0.f; }

    for (int i = 0; i < 64; ++i) {
        float2 wv = *(const float2*)(Wbase + i * 65536);
#pragma unroll
        for (int b = 0; b < 8; ++b) {
            float2 yv = *(const float2*)(Yb + (b * 64 + i) * 2048);
            acc[b][0] += yv.x * wv.x;
            acc[b][1] += yv.y * wv.y;
        }
    }
#pragma unroll
    for (int b = 0; b < 8; ++b) {
        float2 r; r.x = acc[b][0]; r.y = acc[b][1];
        *(float2*)(Z + (size_t)(b * 64 + o) * 2048 + xp * 32 + y) = r;
    }
}

// ---------------- inverse projection: out[b,o,h,w] ----------------
__global__ __launch_bounds__(256) void inv_kernel(const float* __restrict__ ws,
                                                  const float* __restrict__ Zv,
                                                  float* __restrict__ out) {
    __shared__ float zs[2048];     // Z slice [64 r][32 y]
    __shared__ float dmts[8192];   // DmT [32 y][256 w]
    __shared__ float t2t[4224];    // T2 transposed, half-h: [32 y][132]
    const int t = threadIdx.x;
    const int bo = blockIdx.x;
    const float* Zp = Zv + (size_t)bo * 2048;
    float* op = out + (size_t)bo * 65536;

    *(float4*)&zs[t * 8]     = *(const float4*)(Zp + t * 8);
    *(float4*)&zs[t * 8 + 4] = *(const float4*)(Zp + t * 8 + 4);
#pragma unroll
    for (int k = 0; k < 8; ++k)
        *(float4*)&dmts[k * 1024 + t * 4] =
            *(const float4*)(ws + OFF_DMT + k * 1024 + t * 4);
    __syncthreads();

    const int l6 = t & 63;
    const int y8 = (t >> 6) * 8;
    const int l5 = t & 31;
    const int j  = t >> 5;

    for (int hh = 0; hh < 2; ++hh) {
        // stage 1: T2[h][y] = sum_r CmT[r][h] * Z[r][y], h = hh*128 + {l6, l6+64}
        float a1[2][8];
#pragma unroll
        for (int jj = 0; jj < 2; ++jj)
#pragma unroll
            for (int yy = 0; yy < 8; ++yy) a1[jj][yy] = 0.f;
        const float* Cm = ws + OFF_CMT + hh * 128 + l6;
#pragma unroll 4
        for (int xpi = 0; xpi < 64; ++xpi) {
            float av0 = Cm[xpi * 256];          // lane-consecutive: coalesced
            float av1 = Cm[xpi * 256 + 64];
            float4 z0 = *(float4*)&zs[xpi * 32 + y8];       // broadcast
            float4 z1 = *(float4*)&zs[xpi * 32 + y8 + 4];
            float zv[8] = {z0.x, z0.y, z0.z, z0.w, z1.x, z1.y, z1.z, z1.w};
#pragma unroll
            for (int yy = 0; yy < 8; ++yy) {
                a1[0][yy] += av0 * zv[yy];
                a1[1][yy] += av1 * zv[yy];
            }
        }
#pragma unroll
        for (int jj = 0; jj < 2; ++jj)
#pragma unroll
            for (int yy = 0; yy < 8; ++yy)
                t2t[(y8 + yy) * 132 + l6 + 64 * jj] = a1[jj][yy];  // bank (4y+l)%32: free
        __syncthreads();

        // stage 2: out[h][w] = sum_y T2[h][y] * DmT[y][w]; 8h x 8w register tile
        for (int hg = 0; hg < 2; ++hg) {
            float a2[8][8];
#pragma unroll
            for (int ii = 0; ii < 8; ++ii)
#pragma unroll
                for (int ww = 0; ww < 8; ++ww) a2[ii][ww] = 0.f;
            const int hb = hg * 64 + j * 8;
#pragma unroll 4
            for (int y = 0; y < 32; ++y) {
                float4 ta = *(float4*)&t2t[y * 132 + hb];       // 2-way broadcast
                float4 tb = *(float4*)&t2t[y * 132 + hb + 4];
                float4 da = *(float4*)&dmts[y * 256 + l5 * 8];
                float4 db = *(float4*)&dmts[y * 256 + l5 * 8 + 4];
                float tv[8] = {ta.x, ta.y, ta.z, ta.w, tb.x, tb.y, tb.z, tb.w};
                float dv[8] = {da.x, da.y, da.z, da.w, db.x, db.y, db.z, db.w};
#pragma unroll
                for (int ii = 0; ii < 8; ++ii)
#pragma unroll
                    for (int ww = 0; ww < 8; ++ww)
                        a2[ii][ww] += tv[ii] * dv[ww];
            }
#pragma unroll
            for (int ii = 0; ii < 8; ++ii) {
                int h = hh * 128 + hb + ii;
                float* o8 = op + h * 256 + l5 * 8;
                *(float4*)o8       = make_float4(a2[ii][0], a2[ii][1], a2[ii][2], a2[ii][3]);
                *(float4*)(o8 + 4) = make_float4(a2[ii][4], a2[ii][5], a2[ii][6], a2[ii][7]);
            }
        }
        __syncthreads();
    }
}

extern "C" void kernel_launch(void* const* d_in, const int* in_sizes, int n_in,
                              void* d_out, int out_size, void* d_ws, size_t ws_size,
                              hipStream_t stream) {
    const float* x  = (const float*)d_in[0];
    const float* w1 = (const float*)d_in[1];
    const float* w2 = (const float*)d_in[2];
    float* out = (float*)d_out;
    float* ws  = (float*)d_ws;   // needs ~8.6 MB

    hipLaunchKernelGGL(init_basis, dim3(192), dim3(256), 0, stream, ws);
    hipLaunchKernelGGL(fwd_kernel, dim3(512), dim3(256), 0, stream, x, ws, ws + OFF_Y);
    hipLaunchKernelGGL(mix_kernel, dim3(256), dim3(256), 0, stream, w1, w2,
                       ws + OFF_Y, ws + OFF_Z);
    hipLaunchKernelGGL(inv_kernel, dim3(512), dim3(256), 0, stream, ws, ws + OFF_Z, out);
}